// Round 13
// baseline (2139.014 us; speedup 1.0000x reference)
//
#include <hip/hip_runtime.h>
#include <hip/hip_cooperative_groups.h>
#include <hip/hip_bf16.h>
#include <hip/hip_fp16.h>

namespace cg = cooperative_groups;

#define DD 128
#define BN_EPS 1e-5f
#define MEGA_GRID 1024
#define SPMM_BLOCKS 2048     // fallback spmm grid
#define SCAT_BLOCKS 2048     // fallback scatter blocks
#define CAP 32
#define OVF_MAX 8192

typedef __attribute__((ext_vector_type(8))) short bf16x8;
typedef __attribute__((ext_vector_type(4))) float f32x4;

static __device__ __forceinline__ unsigned short f2bf(float f) {
    __hip_bfloat16 h = __float2bfloat16(f);   // RNE
    return *reinterpret_cast<unsigned short*>(&h);
}
static __device__ __forceinline__ float bf2f(unsigned short u) {
    return __uint_as_float(((unsigned)u) << 16);
}
static __device__ __forceinline__ unsigned pack_rec(int col, float val) {
    __half h = __float2half(val);
    unsigned hb = *reinterpret_cast<unsigned short*>(&h);
    return (unsigned)col | (hb << 16);
}
static __device__ __forceinline__ float rec_val(unsigned rec) {
    unsigned short hb = (unsigned short)(rec >> 16);
    __half h = *reinterpret_cast<__half*>(&hb);
    return __half2float(h);
}

// ================================================================ device bodies

// weight transpose+convert: one (mat, chunk) slab, 256 threads
static __device__ __forceinline__ void dev_prep_w(
    int mat, int chunk, const float* __restrict__ W,
    const float* __restrict__ Wself, unsigned short* __restrict__ Wt4)
{
    int layer = mat >> 1;
    const float* src = (mat & 1) ? (Wself + layer * 16384) : (W + layer * 16384);
    unsigned short* dst = Wt4 + (size_t)mat * 16384;
    int base = chunk * 2048 + threadIdx.x * 4;
    #pragma unroll
    for (int rep = 0; rep < 2; rep++) {
        int i = base + rep * 1024;          // i = k*128 + n
        float4 v = *(const float4*)&src[i];
        int k = i >> 7, n = i & 127;
        dst[(n + 0) * 128 + k] = f2bf(v.x);
        dst[(n + 1) * 128 + k] = f2bf(v.y);
        dst[(n + 2) * 128 + k] = f2bf(v.z);
        dst[(n + 3) * 128 + k] = f2bf(v.w);
    }
}

// XCD-affine bucket scatter: slice of edges, keep rows in partition p
static __device__ __forceinline__ void dev_scatter(
    int slice, int nsl, int p,
    const int* __restrict__ arow, const int* __restrict__ acol,
    const float* __restrict__ aval, int* __restrict__ cnt,
    unsigned* __restrict__ bucket, int* __restrict__ ovfc,
    int2* __restrict__ ovf, int E, int rpp)
{
    const int e0 = (int)((long long)E * slice / nsl);
    const int e1 = (int)((long long)E * (slice + 1) / nsl);
    for (int e = e0 + threadIdx.x; e < e1; e += 256) {
        int r = arow[e];
        if (r / rpp == p) {
            int pos = atomicAdd(&cnt[r], 1);
            unsigned rec = pack_rec(acol[e], aval[e]);
            if (pos < CAP) {
                bucket[(size_t)r * CAP + pos] = rec;
            } else {
                int oi = atomicAdd(ovfc, 1);
                if (oi < OVF_MAX) ovf[oi] = make_int2(r, (int)rec);
            }
        }
    }
}

// one 64-row x 128-col GEMM tile; low-VGPR (stores per n-tile)
// support = bf16(A'@Wt), outb = A'@Wst + bias;  A' = useBN ? relu(A*sc+sh) : A
static __device__ __forceinline__ void dev_gemm_tile(
    int t, const float* __restrict__ A,
    const unsigned short* __restrict__ Wt, const unsigned short* __restrict__ Wst,
    const float* __restrict__ bias, const float* ssc, const float* ssh, int useBN,
    unsigned short* __restrict__ support, float* __restrict__ outb, int N)
{
    const int wave = threadIdx.x >> 6;
    const int lane = threadIdx.x & 63;
    const int m    = lane & 15;
    const int quad = lane >> 4;
    const int row0 = t * 64 + wave * 16;

    int ar = row0 + m; if (ar > N - 1) ar = N - 1;
    const float* Ar = A + (size_t)ar * 128;
    bf16x8 af[4];
    #pragma unroll
    for (int ch = 0; ch < 4; ch++) {
        int k0 = ch * 32 + quad * 8;
        float4 u = *(const float4*)&Ar[k0];
        float4 v = *(const float4*)&Ar[k0 + 4];
        float vals[8] = {u.x, u.y, u.z, u.w, v.x, v.y, v.z, v.w};
        #pragma unroll
        for (int j = 0; j < 8; j++) {
            float val = vals[j];
            if (useBN) {
                val = val * ssc[k0 + j] + ssh[k0 + j];
                val = val > 0.f ? val : 0.f;
            }
            af[ch][j] = (short)f2bf(val);
        }
    }

    #pragma unroll
    for (int nt = 0; nt < 8; nt++) {
        const bf16x8* B1 = (const bf16x8*)(Wt  + ((size_t)(nt * 16 + m)) * 128 + quad * 8);
        const bf16x8* B2 = (const bf16x8*)(Wst + ((size_t)(nt * 16 + m)) * 128 + quad * 8);
        f32x4 a1 = (f32x4)(0.f), a2 = (f32x4)(0.f);
        a1 = __builtin_amdgcn_mfma_f32_16x16x32_bf16(af[0], B1[0],  a1, 0, 0, 0);
        a2 = __builtin_amdgcn_mfma_f32_16x16x32_bf16(af[0], B2[0],  a2, 0, 0, 0);
        a1 = __builtin_amdgcn_mfma_f32_16x16x32_bf16(af[1], B1[4],  a1, 0, 0, 0);
        a2 = __builtin_amdgcn_mfma_f32_16x16x32_bf16(af[1], B2[4],  a2, 0, 0, 0);
        a1 = __builtin_amdgcn_mfma_f32_16x16x32_bf16(af[2], B1[8],  a1, 0, 0, 0);
        a2 = __builtin_amdgcn_mfma_f32_16x16x32_bf16(af[2], B2[8],  a2, 0, 0, 0);
        a1 = __builtin_amdgcn_mfma_f32_16x16x32_bf16(af[3], B1[12], a1, 0, 0, 0);
        a2 = __builtin_amdgcn_mfma_f32_16x16x32_bf16(af[3], B2[12], a2, 0, 0, 0);
        float bvn = bias[nt * 16 + m];
        // C/D layout: col = lane&15, row = quad*4 + reg
        #pragma unroll
        for (int r = 0; r < 4; r++) {
            int orow = row0 + quad * 4 + r;
            if (orow < N) {
                size_t base = (size_t)orow * 128 + m + nt * 16;
                support[base] = f2bf(a1[r]);
                outb[base]    = a2[r] + bvn;
            }
        }
    }
}

// SpMM over buckets + per-block BN-stat partials (non-atomic)
static __device__ void dev_spmm_stats(
    const int* __restrict__ cnt, const unsigned* __restrict__ bucket,
    const int* __restrict__ ovfc, const int2* __restrict__ ovf,
    const unsigned short* __restrict__ sup, float* __restrict__ outb,
    float* __restrict__ partials, int ngroups, int N, int nb,
    float (*red)[128])
{
    const int r    = threadIdx.x & 31;
    const int slot = threadIdx.x >> 5;
    float s4[4] = {0.f, 0.f, 0.f, 0.f};
    float q4[4] = {0.f, 0.f, 0.f, 0.f};

    for (int g = blockIdx.x; g < ngroups; g += nb) {
        int row = g * 8 + slot;
        if (row >= N) continue;
        int nrec = cnt[row]; if (nrec > CAP) nrec = CAP;
        const unsigned* packed = bucket + (size_t)row * CAP;

        float4 acc = make_float4(0.f, 0.f, 0.f, 0.f);
        int e = 0;
        for (; e + 4 <= nrec; e += 4) {
            unsigned p0 = packed[e + 0];
            unsigned p1 = packed[e + 1];
            unsigned p2 = packed[e + 2];
            unsigned p3 = packed[e + 3];
            ushort4 s0 = *(const ushort4*)&sup[((size_t)(p0 & 0xFFFFu) << 7) + r * 4];
            ushort4 s1 = *(const ushort4*)&sup[((size_t)(p1 & 0xFFFFu) << 7) + r * 4];
            ushort4 s2 = *(const ushort4*)&sup[((size_t)(p2 & 0xFFFFu) << 7) + r * 4];
            ushort4 s3 = *(const ushort4*)&sup[((size_t)(p3 & 0xFFFFu) << 7) + r * 4];
            float v0 = rec_val(p0), v1 = rec_val(p1);
            float v2 = rec_val(p2), v3 = rec_val(p3);
            acc.x += v0 * bf2f(s0.x); acc.y += v0 * bf2f(s0.y);
            acc.z += v0 * bf2f(s0.z); acc.w += v0 * bf2f(s0.w);
            acc.x += v1 * bf2f(s1.x); acc.y += v1 * bf2f(s1.y);
            acc.z += v1 * bf2f(s1.z); acc.w += v1 * bf2f(s1.w);
            acc.x += v2 * bf2f(s2.x); acc.y += v2 * bf2f(s2.y);
            acc.z += v2 * bf2f(s2.z); acc.w += v2 * bf2f(s2.w);
            acc.x += v3 * bf2f(s3.x); acc.y += v3 * bf2f(s3.y);
            acc.z += v3 * bf2f(s3.z); acc.w += v3 * bf2f(s3.w);
        }
        for (; e < nrec; e++) {
            unsigned pr = packed[e];
            ushort4 sv = *(const ushort4*)&sup[((size_t)(pr & 0xFFFFu) << 7) + r * 4];
            float v = rec_val(pr);
            acc.x += v * bf2f(sv.x); acc.y += v * bf2f(sv.y);
            acc.z += v * bf2f(sv.z); acc.w += v * bf2f(sv.w);
        }

        int oc = *ovfc;
        if (oc > 0) {                     // rare exactness safety net
            if (oc > OVF_MAX) oc = OVF_MAX;
            for (int i = 0; i < oc; i++) {
                int2 orec = ovf[i];
                if (orec.x == row) {
                    unsigned pr = (unsigned)orec.y;
                    ushort4 sv = *(const ushort4*)&sup[((size_t)(pr & 0xFFFFu) << 7) + r * 4];
                    float v = rec_val(pr);
                    acc.x += v * bf2f(sv.x); acc.y += v * bf2f(sv.y);
                    acc.z += v * bf2f(sv.z); acc.w += v * bf2f(sv.w);
                }
            }
        }

        float4* op = (float4*)&outb[((size_t)row << 7) + r * 4];
        float4 o = *op;
        o.x += acc.x; o.y += acc.y; o.z += acc.z; o.w += acc.w;
        *op = o;
        s4[0] += o.x; s4[1] += o.y; s4[2] += o.z; s4[3] += o.w;
        q4[0] += o.x * o.x; q4[1] += o.y * o.y; q4[2] += o.z * o.z; q4[3] += o.w * o.w;
    }

    #pragma unroll
    for (int j = 0; j < 4; j++) red[slot][r * 4 + j] = s4[j];
    __syncthreads();
    float ts = 0.f;
    if (threadIdx.x < 128) {
        #pragma unroll
        for (int j = 0; j < 8; j++) ts += red[j][threadIdx.x];
        partials[(size_t)blockIdx.x * 256 + threadIdx.x] = ts;
    }
    __syncthreads();
    #pragma unroll
    for (int j = 0; j < 4; j++) red[slot][r * 4 + j] = q4[j];
    __syncthreads();
    if (threadIdx.x < 128) {
        float tq = 0.f;
        #pragma unroll
        for (int j = 0; j < 8; j++) tq += red[j][threadIdx.x];
        partials[(size_t)blockIdx.x * 256 + 128 + threadIdx.x] = tq;
    }
    __syncthreads();
}

// ================================================================ MEGA kernel
__global__ __launch_bounds__(256, 4) void mega(
    const float* __restrict__ x, const int* __restrict__ arow,
    const int* __restrict__ acol, const float* __restrict__ aval,
    const int* __restrict__ ei,
    const float* __restrict__ W, const float* __restrict__ Wself,
    const float* __restrict__ b, const float* __restrict__ gamma,
    const float* __restrict__ beta, const float* __restrict__ Wc,
    const float* __restrict__ bc, float* __restrict__ outp,
    unsigned short* support16, float* outbA, float* outbB,
    unsigned short* Wt4, float* stats, int* cnt, int* ovfc,
    unsigned* bucket, int2* ovf, float* s1, float* s2, float* partials,
    int N, int E, int Ep, float invN, int gemm_tiles, int ngroups)
{
    cg::grid_group grid = cg::this_grid();
    const int nb  = gridDim.x;
    const int tid = threadIdx.x;
    const int rpp = (N + 7) / 8;
    __shared__ float sh_a[128], sh_b[128];
    __shared__ float red[8][128];

    // ---- P0: weight prep + zero (stats | cnt | ovfc contiguous) ----
    if (blockIdx.x < 32) {
        dev_prep_w(blockIdx.x >> 3, blockIdx.x & 7, W, Wself, Wt4);
    } else {
        int nz = 512 + N + 1;
        int i = (blockIdx.x - 32) * 256 + tid;
        if (i < nz) ((int*)stats)[i] = 0;
    }
    __threadfence();
    grid.sync();

    // ---- P1: scatter + gemm L0 (staggered for pipe overlap) ----
    if (blockIdx.x & 1) {
        if (blockIdx.x < gemm_tiles)
            dev_gemm_tile(blockIdx.x, x, Wt4, Wt4 + 16384, b, sh_a, sh_b, 0,
                          support16, outbA, N);
        dev_scatter(blockIdx.x >> 3, nb >> 3, blockIdx.x & 7,
                    arow, acol, aval, cnt, bucket, ovfc, ovf, E, rpp);
    } else {
        dev_scatter(blockIdx.x >> 3, nb >> 3, blockIdx.x & 7,
                    arow, acol, aval, cnt, bucket, ovfc, ovf, E, rpp);
        if (blockIdx.x < gemm_tiles)
            dev_gemm_tile(blockIdx.x, x, Wt4, Wt4 + 16384, b, sh_a, sh_b, 0,
                          support16, outbA, N);
    }
    __threadfence();
    grid.sync();

    // ---- P2: spmm L0 + stat partials ----
    dev_spmm_stats(cnt, bucket, ovfc, ovf, support16, outbA, partials, ngroups, N, nb, red);
    __threadfence();
    grid.sync();

    // ---- P3: reduce partials -> stats[0..255] ----
    if (blockIdx.x < 32) {
        int per = nb >> 5;
        float a = 0.f;
        for (int i = 0; i < per; i++)
            a += partials[(size_t)(blockIdx.x * per + i) * 256 + tid];
        atomicAdd(&stats[tid], a);
    }
    __threadfence();
    grid.sync();

    // ---- P4: gemm L1 with fused BN(L0) on A ----
    if (tid < 128) {
        float mean = stats[tid] * invN;
        float var  = stats[128 + tid] * invN - mean * mean;
        float sc   = gamma[tid] * rsqrtf(var + BN_EPS);
        sh_a[tid] = sc;
        sh_b[tid] = beta[tid] - mean * sc;
    }
    __syncthreads();
    for (int t = blockIdx.x; t < gemm_tiles; t += nb)
        dev_gemm_tile(t, outbA, Wt4 + 2 * 16384, Wt4 + 3 * 16384, b + DD,
                      sh_a, sh_b, 1, support16, outbB, N);
    __threadfence();
    grid.sync();

    // ---- P5: spmm L1 + stat partials ----
    dev_spmm_stats(cnt, bucket, ovfc, ovf, support16, outbB, partials, ngroups, N, nb, red);
    __threadfence();
    grid.sync();

    // ---- P6: reduce partials -> stats[256..511] ----
    if (blockIdx.x < 32) {
        int per = nb >> 5;
        float a = 0.f;
        for (int i = 0; i < per; i++)
            a += partials[(size_t)(blockIdx.x * per + i) * 256 + tid];
        atomicAdd(&stats[256 + tid], a);
    }
    __threadfence();
    grid.sync();

    // ---- P7: BN(L1) + residual + factorized score -> s1, s2 ----
    {
        const float* st = stats + 256;
        const float* g2 = gamma + DD;
        const float* b2 = beta + DD;
        int total = N * 32;
        int stride = nb * 256;
        for (int idx = blockIdx.x * 256 + tid; idx < total; idx += stride) {
            int c4 = (idx & 31) * 4;
            float4 o = *(const float4*)&outbB[(size_t)idx * 4];
            float res[4];
            const float* op = &o.x;
            #pragma unroll
            for (int j = 0; j < 4; j++) {
                int c = c4 + j;
                float mean = st[c] * invN;
                float var  = st[128 + c] * invN - mean * mean;
                float sc   = g2[c] * rsqrtf(var + BN_EPS);
                float sh   = b2[c] - mean * sc;
                float v    = op[j] * sc + sh;
                res[j] = v > 0.f ? v : 0.f;
            }
            float4 xv = *(const float4*)&x[(size_t)idx * 4];
            res[0] += xv.x; res[1] += xv.y; res[2] += xv.z; res[3] += xv.w;
            float4 w1 = *(const float4*)&Wc[c4];
            float4 w2 = *(const float4*)&Wc[128 + c4];
            float a1 = res[0] * w1.x + res[1] * w1.y + res[2] * w1.z + res[3] * w1.w;
            float a2 = res[0] * w2.x + res[1] * w2.y + res[2] * w2.z + res[3] * w2.w;
            #pragma unroll
            for (int off = 1; off < 32; off <<= 1) {
                a1 += __shfl_xor(a1, off);
                a2 += __shfl_xor(a2, off);
            }
            if ((idx & 31) == 0) {
                int row = idx >> 5;
                s1[row] = a1;
                s2[row] = a2;
            }
        }
    }
    __threadfence();
    grid.sync();

    // ---- P8: edge predictor ----
    {
        float bias = bc[0];
        for (int e = blockIdx.x * 256 + tid; e < Ep; e += nb * 256) {
            float v = s1[ei[e]] + s2[ei[Ep + e]] + bias;
            outp[e] = 1.f / (1.f + expf(-v));
        }
    }
}

// ================================================================ fallback kernels
__global__ __launch_bounds__(256) void prep_zero_k(
    const float* __restrict__ W, const float* __restrict__ Wself,
    unsigned short* __restrict__ Wt4, int* __restrict__ zp, int nz)
{
    if (blockIdx.x < 32) {
        dev_prep_w(blockIdx.x >> 3, blockIdx.x & 7, W, Wself, Wt4);
    } else {
        int i = (blockIdx.x - 32) * 256 + threadIdx.x;
        if (i < nz) zp[i] = 0;
    }
}

__global__ __launch_bounds__(256) void gemm_l0_scatter_k(
    const float* __restrict__ A,
    const unsigned short* __restrict__ Wt, const unsigned short* __restrict__ Wst,
    const float* __restrict__ bias,
    unsigned short* __restrict__ support, float* __restrict__ outb, int N,
    const int* __restrict__ arow, const int* __restrict__ acol,
    const float* __restrict__ aval, int* __restrict__ cnt,
    unsigned* __restrict__ bucket, int* __restrict__ ovfc,
    int2* __restrict__ ovf, int E, int rpp)
{
    if (blockIdx.x < SCAT_BLOCKS) {   // scatter first: preserves blockIdx%8 affinity
        dev_scatter(blockIdx.x >> 3, SCAT_BLOCKS >> 3, blockIdx.x & 7,
                    arow, acol, aval, cnt, bucket, ovfc, ovf, E, rpp);
        return;
    }
    dev_gemm_tile(blockIdx.x - SCAT_BLOCKS, A, Wt, Wst, bias,
                  nullptr, nullptr, 0, support, outb, N);
}

__global__ __launch_bounds__(256) void gemm_bn_k(
    const float* __restrict__ A,
    const unsigned short* __restrict__ Wt, const unsigned short* __restrict__ Wst,
    const float* __restrict__ bias,
    const float* __restrict__ stats, const float* __restrict__ gamma,
    const float* __restrict__ beta, float invN,
    unsigned short* __restrict__ support, float* __restrict__ outb, int N)
{
    __shared__ float sa[128], sb[128];
    if (threadIdx.x < 128) {
        int c = threadIdx.x;
        float mean = stats[c] * invN;
        float var  = stats[128 + c] * invN - mean * mean;
        float sc   = gamma[c] * rsqrtf(var + BN_EPS);
        sa[c] = sc;
        sb[c] = beta[c] - mean * sc;
    }
    __syncthreads();
    dev_gemm_tile(blockIdx.x, A, Wt, Wst, bias, sa, sb, 1, support, outb, N);
}

__global__ __launch_bounds__(256) void spmm_stats_k(
    const int* __restrict__ cnt, const unsigned* __restrict__ bucket,
    const int* __restrict__ ovfc, const int2* __restrict__ ovf,
    const unsigned short* __restrict__ sup, float* __restrict__ outb,
    float* __restrict__ partials, int ngroups, int N)
{
    __shared__ float red[8][128];
    dev_spmm_stats(cnt, bucket, ovfc, ovf, sup, outb, partials, ngroups, N, gridDim.x, red);
}

__global__ __launch_bounds__(256) void reduce_stats_k(
    const float* __restrict__ partials, float* __restrict__ stats, int nblk)
{
    int per = (nblk + gridDim.x - 1) / gridDim.x;
    int b0 = blockIdx.x * per, b1 = min(b0 + per, nblk);
    float a0 = 0.f;
    for (int b = b0; b < b1; b++)
        a0 += partials[(size_t)b * 256 + threadIdx.x];
    atomicAdd(&stats[threadIdx.x], a0);
}

__global__ __launch_bounds__(256) void score_k(
    const float* __restrict__ outb, const float* __restrict__ stats,
    const float* __restrict__ gamma, const float* __restrict__ beta,
    const float* __restrict__ x, const float* __restrict__ Wc,
    float* __restrict__ s1, float* __restrict__ s2, float invN, int N)
{
    int idx = blockIdx.x * 256 + threadIdx.x;
    if (idx >= N * 32) return;
    int c4 = (idx & 31) * 4;
    float4 o = *(const float4*)&outb[(size_t)idx * 4];
    float res[4];
    const float* op = &o.x;
    #pragma unroll
    for (int j = 0; j < 4; j++) {
        int c = c4 + j;
        float mean = stats[c] * invN;
        float var  = stats[128 + c] * invN - mean * mean;
        float sc   = gamma[c] * rsqrtf(var + BN_EPS);
        float sh   = beta[c] - mean * sc;
        float v    = op[j] * sc + sh;
        res[j] = v > 0.f ? v : 0.f;
    }
    float4 xv = *(const float4*)&x[(size_t)idx * 4];
    res[0] += xv.x; res[1] += xv.y; res[2] += xv.z; res[3] += xv.w;
    float4 w1 = *(const float4*)&Wc[c4];
    float4 w2 = *(const float4*)&Wc[128 + c4];
    float a1 = res[0] * w1.x + res[1] * w1.y + res[2] * w1.z + res[3] * w1.w;
    float a2 = res[0] * w2.x + res[1] * w2.y + res[2] * w2.z + res[3] * w2.w;
    #pragma unroll
    for (int off = 1; off < 32; off <<= 1) {
        a1 += __shfl_xor(a1, off);
        a2 += __shfl_xor(a2, off);
    }
    if ((idx & 31) == 0) {
        int row = idx >> 5;
        s1[row] = a1;
        s2[row] = a2;
    }
}

__global__ __launch_bounds__(256) void edge_pred_k(
    const float* __restrict__ s1, const float* __restrict__ s2,
    const int* __restrict__ ei, const float* __restrict__ bc,
    float* __restrict__ outp, int Ep)
{
    int e = blockIdx.x * 256 + threadIdx.x;
    if (e >= Ep) return;
    float v = s1[ei[e]] + s2[ei[Ep + e]] + bc[0];
    outp[e] = 1.f / (1.f + expf(-v));
}

// ================================================================ launch
extern "C" void kernel_launch(void* const* d_in, const int* in_sizes, int n_in,
                              void* d_out, int out_size, void* d_ws, size_t ws_size,
                              hipStream_t stream) {
    const float* x        = (const float*)d_in[0];
    const int*   adj_row  = (const int*)  d_in[1];
    const int*   adj_col  = (const int*)  d_in[2];
    const float* adj_val  = (const float*)d_in[3];
    const int*   ei       = (const int*)  d_in[4];
    const float* W        = (const float*)d_in[5];
    const float* W_self   = (const float*)d_in[6];
    const float* b        = (const float*)d_in[7];
    const float* gamma    = (const float*)d_in[8];
    const float* beta     = (const float*)d_in[9];
    const float* Wc       = (const float*)d_in[10];
    const float* bc       = (const float*)d_in[11];
    float* outp = (float*)d_out;

    int N  = in_sizes[0] / DD;    // 50000
    int E  = in_sizes[1];         // 800000
    int Ep = in_sizes[4] / 2;     // 500000
    float invN = 1.f / (float)N;

    size_t nd = (size_t)N * DD;
    char* p = (char*)d_ws;
    unsigned short* support16 = (unsigned short*)p; p += nd * 2;
    float*          outbA     = (float*)p;          p += nd * 4;
    float*          outbB     = (float*)p;          p += nd * 4;
    unsigned short* Wt4       = (unsigned short*)p; p += 4 * 16384 * 2;
    float*          stats     = (float*)p;          p += 512 * 4;       // [L0|L1]
    int*            cnt       = (int*)p;            p += (size_t)N * 4; // contiguous w/ stats
    int*            ovfc      = (int*)p;            p += 4;             // contiguous w/ cnt
    unsigned*       bucket    = (unsigned*)p;       p += (size_t)N * CAP * 4;
    int2*           ovf       = (int2*)p;           p += (size_t)OVF_MAX * 8;
    float*          s1        = (float*)p;          p += (size_t)N * 4;
    float*          s2        = (float*)p;          p += (size_t)N * 4;
    float*          partials  = (float*)p;          p += (size_t)SPMM_BLOCKS * 256 * 4;

    int gemm_tiles = (N + 63) / 64;
    int ngroups    = (N + 7) / 8;
    int rpp        = (N + 7) / 8;
    int nz         = 512 + N + 1;

    void* kargs[] = {
        (void*)&x, (void*)&adj_row, (void*)&adj_col, (void*)&adj_val, (void*)&ei,
        (void*)&W, (void*)&W_self, (void*)&b, (void*)&gamma, (void*)&beta,
        (void*)&Wc, (void*)&bc, (void*)&outp,
        (void*)&support16, (void*)&outbA, (void*)&outbB, (void*)&Wt4,
        (void*)&stats, (void*)&cnt, (void*)&ovfc, (void*)&bucket, (void*)&ovf,
        (void*)&s1, (void*)&s2, (void*)&partials,
        (void*)&N, (void*)&E, (void*)&Ep, (void*)&invN, (void*)&gemm_tiles, (void*)&ngroups
    };

    hipError_t rc = hipLaunchCooperativeKernel(
        (const void*)mega, dim3(MEGA_GRID), dim3(256), kargs, 0, stream);

    if (rc != hipSuccess) {
        // ---------------- fallback: separate launches (R12-equivalent) ----------------
        prep_zero_k<<<32 + (nz + 255) / 256, 256, 0, stream>>>(W, W_self, Wt4, (int*)stats, nz);
        gemm_l0_scatter_k<<<SCAT_BLOCKS + gemm_tiles, 256, 0, stream>>>(
            x, Wt4, Wt4 + 16384, b, support16, outbA, N,
            adj_row, adj_col, adj_val, cnt, bucket, ovfc, ovf, E, rpp);
        spmm_stats_k<<<SPMM_BLOCKS, 256, 0, stream>>>(
            cnt, bucket, ovfc, ovf, support16, outbA, partials, ngroups, N);
        reduce_stats_k<<<32, 256, 0, stream>>>(partials, stats, SPMM_BLOCKS);
        gemm_bn_k<<<gemm_tiles, 256, 0, stream>>>(
            outbA, Wt4 + 2 * 16384, Wt4 + 3 * 16384, b + DD,
            stats, gamma, beta, invN, support16, outbB, N);
        spmm_stats_k<<<SPMM_BLOCKS, 256, 0, stream>>>(
            cnt, bucket, ovfc, ovf, support16, outbB, partials, ngroups, N);
        reduce_stats_k<<<32, 256, 0, stream>>>(partials, stats + 256, SPMM_BLOCKS);
        score_k<<<(N * 32 + 255) / 256, 256, 0, stream>>>(
            outbB, stats + 256, gamma + DD, beta + DD, x, Wc, s1, s2, invN, N);
        edge_pred_k<<<(Ep + 255) / 256, 256, 0, stream>>>(s1, s2, ei, bc, outp, Ep);
    }
}

// Round 14
// 389.600 us; speedup vs baseline: 5.4903x; 5.4903x over previous
//
#include <hip/hip_runtime.h>
#include <hip/hip_bf16.h>
#include <hip/hip_fp16.h>

#define DD 128
#define BN_EPS 1e-5f
#define SPMM_BLOCKS 2048
#define FUSE_GRID 2048       // 256 CUs x 8 blocks co-resident; blockIdx%8 ~ XCD
#define NSLOT 64             // stat partial slots
#define CAP 32
#define OVF_MAX 8192

typedef __attribute__((ext_vector_type(8))) short bf16x8;
typedef __attribute__((ext_vector_type(4))) float f32x4;

static __device__ __forceinline__ unsigned short f2bf(float f) {
    __hip_bfloat16 h = __float2bfloat16(f);   // RNE
    return *reinterpret_cast<unsigned short*>(&h);
}
static __device__ __forceinline__ float bf2f(unsigned short u) {
    return __uint_as_float(((unsigned)u) << 16);
}
static __device__ __forceinline__ unsigned pack_rec(int col, float val) {
    __half h = __float2half(val);
    unsigned hb = *reinterpret_cast<unsigned short*>(&h);
    return (unsigned)col | (hb << 16);
}
static __device__ __forceinline__ float rec_val(unsigned rec) {
    unsigned short hb = (unsigned short)(rec >> 16);
    __half h = *reinterpret_cast<__half*>(&hb);
    return __half2float(h);
}

// ================================================================ device bodies
static __device__ __forceinline__ void dev_prep_w(
    int mat, int chunk, const float* __restrict__ W,
    const float* __restrict__ Wself, unsigned short* __restrict__ Wt4)
{
    int layer = mat >> 1;
    const float* src = (mat & 1) ? (Wself + layer * 16384) : (W + layer * 16384);
    unsigned short* dst = Wt4 + (size_t)mat * 16384;
    int base = chunk * 2048 + threadIdx.x * 4;
    #pragma unroll
    for (int rep = 0; rep < 2; rep++) {
        int i = base + rep * 1024;          // i = k*128 + n
        float4 v = *(const float4*)&src[i];
        int k = i >> 7, n = i & 127;
        dst[(n + 0) * 128 + k] = f2bf(v.x);
        dst[(n + 1) * 128 + k] = f2bf(v.y);
        dst[(n + 2) * 128 + k] = f2bf(v.z);
        dst[(n + 3) * 128 + k] = f2bf(v.w);
    }
}

static __device__ __forceinline__ void dev_scatter(
    int slice, int nsl, int p,
    const int* __restrict__ arow, const int* __restrict__ acol,
    const float* __restrict__ aval, int* __restrict__ cnt,
    unsigned* __restrict__ bucket, int* __restrict__ ovfc,
    int2* __restrict__ ovf, int E, int rpp)
{
    const int e0 = (int)((long long)E * slice / nsl);
    const int e1 = (int)((long long)E * (slice + 1) / nsl);
    for (int e = e0 + threadIdx.x; e < e1; e += 256) {
        int r = arow[e];
        if (r / rpp == p) {
            int pos = atomicAdd(&cnt[r], 1);
            unsigned rec = pack_rec(acol[e], aval[e]);
            if (pos < CAP) {
                bucket[(size_t)r * CAP + pos] = rec;
            } else {
                int oi = atomicAdd(ovfc, 1);
                if (oi < OVF_MAX) ovf[oi] = make_int2(r, (int)rec);
            }
        }
    }
}

// one 64-row x 128-col tile; low-VGPR (per-nt accumulate+store)
static __device__ __forceinline__ void dev_gemm_tile(
    int t, const float* __restrict__ A,
    const unsigned short* __restrict__ Wt, const unsigned short* __restrict__ Wst,
    const float* __restrict__ bias, const float* ssc, const float* ssh, int useBN,
    unsigned short* __restrict__ support, float* __restrict__ outb, int N)
{
    const int wave = threadIdx.x >> 6;
    const int lane = threadIdx.x & 63;
    const int m    = lane & 15;
    const int quad = lane >> 4;
    const int row0 = t * 64 + wave * 16;

    int ar = row0 + m; if (ar > N - 1) ar = N - 1;
    const float* Ar = A + (size_t)ar * 128;
    bf16x8 af[4];
    #pragma unroll
    for (int ch = 0; ch < 4; ch++) {
        int k0 = ch * 32 + quad * 8;
        float4 u = *(const float4*)&Ar[k0];
        float4 v = *(const float4*)&Ar[k0 + 4];
        float vals[8] = {u.x, u.y, u.z, u.w, v.x, v.y, v.z, v.w};
        #pragma unroll
        for (int j = 0; j < 8; j++) {
            float val = vals[j];
            if (useBN) {
                val = val * ssc[k0 + j] + ssh[k0 + j];
                val = val > 0.f ? val : 0.f;
            }
            af[ch][j] = (short)f2bf(val);
        }
    }

    #pragma unroll
    for (int nt = 0; nt < 8; nt++) {
        const bf16x8* B1 = (const bf16x8*)(Wt  + ((size_t)(nt * 16 + m)) * 128 + quad * 8);
        const bf16x8* B2 = (const bf16x8*)(Wst + ((size_t)(nt * 16 + m)) * 128 + quad * 8);
        f32x4 a1 = (f32x4)(0.f), a2 = (f32x4)(0.f);
        a1 = __builtin_amdgcn_mfma_f32_16x16x32_bf16(af[0], B1[0],  a1, 0, 0, 0);
        a2 = __builtin_amdgcn_mfma_f32_16x16x32_bf16(af[0], B2[0],  a2, 0, 0, 0);
        a1 = __builtin_amdgcn_mfma_f32_16x16x32_bf16(af[1], B1[4],  a1, 0, 0, 0);
        a2 = __builtin_amdgcn_mfma_f32_16x16x32_bf16(af[1], B2[4],  a2, 0, 0, 0);
        a1 = __builtin_amdgcn_mfma_f32_16x16x32_bf16(af[2], B1[8],  a1, 0, 0, 0);
        a2 = __builtin_amdgcn_mfma_f32_16x16x32_bf16(af[2], B2[8],  a2, 0, 0, 0);
        a1 = __builtin_amdgcn_mfma_f32_16x16x32_bf16(af[3], B1[12], a1, 0, 0, 0);
        a2 = __builtin_amdgcn_mfma_f32_16x16x32_bf16(af[3], B2[12], a2, 0, 0, 0);
        float bvn = bias[nt * 16 + m];
        // C/D layout: col = lane&15, row = quad*4 + reg
        #pragma unroll
        for (int r = 0; r < 4; r++) {
            int orow = row0 + quad * 4 + r;
            if (orow < N) {
                size_t base = (size_t)orow * 128 + m + nt * 16;
                support[base] = f2bf(a1[r]);
                outb[base]    = a2[r] + bvn;
            }
        }
    }
}

// ================================================================ kernels
// prep weights + zero [partialsA|partialsB|cnt|ovfc]
__global__ __launch_bounds__(256) void prep_zero_k(
    const float* __restrict__ W, const float* __restrict__ Wself,
    unsigned short* __restrict__ Wt4, int* __restrict__ zp, int nz)
{
    if (blockIdx.x < 32) {
        dev_prep_w(blockIdx.x >> 3, blockIdx.x & 7, W, Wself, Wt4);
    } else {
        int i = (blockIdx.x - 32) * 256 + threadIdx.x;
        if (i < nz) zp[i] = 0;
    }
}

// fused scatter + gemm L0, interleaved roles for per-CU overlap:
// group g = blockIdx>>3; g even -> scatter (slice=blockIdx>>4, p=blockIdx&7);
// g odd -> gemm tile t = (blockIdx>>4)*8 + (blockIdx&7), stride FUSE_GRID/2
__global__ __launch_bounds__(256) void gemm_l0_scatter_k(
    const float* __restrict__ A,
    const unsigned short* __restrict__ Wt, const unsigned short* __restrict__ Wst,
    const float* __restrict__ bias,
    unsigned short* __restrict__ support, float* __restrict__ outb, int N, int gemm_tiles,
    const int* __restrict__ arow, const int* __restrict__ acol,
    const float* __restrict__ aval, int* __restrict__ cnt,
    unsigned* __restrict__ bucket, int* __restrict__ ovfc,
    int2* __restrict__ ovf, int E, int rpp)
{
    if (((blockIdx.x >> 3) & 1) == 0) {
        dev_scatter(blockIdx.x >> 4, FUSE_GRID >> 4, blockIdx.x & 7,
                    arow, acol, aval, cnt, bucket, ovfc, ovf, E, rpp);
    } else {
        for (int t = (blockIdx.x >> 4) * 8 + (blockIdx.x & 7); t < gemm_tiles;
             t += (FUSE_GRID >> 1))
            dev_gemm_tile(t, A, Wt, Wst, bias, nullptr, nullptr, 0, support, outb, N);
    }
}

// SpMM over buckets + BN stats into NSLOT-way partials (atomic, low contention)
__global__ __launch_bounds__(256) void spmm_stats_k(
    const int* __restrict__ cnt, const unsigned* __restrict__ bucket,
    const int* __restrict__ ovfc, const int2* __restrict__ ovf,
    const unsigned short* __restrict__ sup, float* __restrict__ outb,
    float* __restrict__ partials, int ngroups, int N)
{
    const int r    = threadIdx.x & 31;
    const int slot = threadIdx.x >> 5;
    float s4[4] = {0.f, 0.f, 0.f, 0.f};
    float q4[4] = {0.f, 0.f, 0.f, 0.f};
    __shared__ float red[8][128];

    for (int g = blockIdx.x; g < ngroups; g += gridDim.x) {
        int row = g * 8 + slot;
        if (row >= N) continue;
        int nrec = cnt[row]; if (nrec > CAP) nrec = CAP;
        const unsigned* packed = bucket + (size_t)row * CAP;

        float4 acc = make_float4(0.f, 0.f, 0.f, 0.f);
        int e = 0;
        for (; e + 4 <= nrec; e += 4) {
            unsigned p0 = packed[e + 0];
            unsigned p1 = packed[e + 1];
            unsigned p2 = packed[e + 2];
            unsigned p3 = packed[e + 3];
            ushort4 s0 = *(const ushort4*)&sup[((size_t)(p0 & 0xFFFFu) << 7) + r * 4];
            ushort4 s1 = *(const ushort4*)&sup[((size_t)(p1 & 0xFFFFu) << 7) + r * 4];
            ushort4 s2 = *(const ushort4*)&sup[((size_t)(p2 & 0xFFFFu) << 7) + r * 4];
            ushort4 s3 = *(const ushort4*)&sup[((size_t)(p3 & 0xFFFFu) << 7) + r * 4];
            float v0 = rec_val(p0), v1 = rec_val(p1);
            float v2 = rec_val(p2), v3 = rec_val(p3);
            acc.x += v0 * bf2f(s0.x); acc.y += v0 * bf2f(s0.y);
            acc.z += v0 * bf2f(s0.z); acc.w += v0 * bf2f(s0.w);
            acc.x += v1 * bf2f(s1.x); acc.y += v1 * bf2f(s1.y);
            acc.z += v1 * bf2f(s1.z); acc.w += v1 * bf2f(s1.w);
            acc.x += v2 * bf2f(s2.x); acc.y += v2 * bf2f(s2.y);
            acc.z += v2 * bf2f(s2.z); acc.w += v2 * bf2f(s2.w);
            acc.x += v3 * bf2f(s3.x); acc.y += v3 * bf2f(s3.y);
            acc.z += v3 * bf2f(s3.z); acc.w += v3 * bf2f(s3.w);
        }
        for (; e < nrec; e++) {
            unsigned pr = packed[e];
            ushort4 sv = *(const ushort4*)&sup[((size_t)(pr & 0xFFFFu) << 7) + r * 4];
            float v = rec_val(pr);
            acc.x += v * bf2f(sv.x); acc.y += v * bf2f(sv.y);
            acc.z += v * bf2f(sv.z); acc.w += v * bf2f(sv.w);
        }

        int oc = *ovfc;
        if (oc > 0) {                     // rare exactness safety net
            if (oc > OVF_MAX) oc = OVF_MAX;
            for (int i = 0; i < oc; i++) {
                int2 orec = ovf[i];
                if (orec.x == row) {
                    unsigned pr = (unsigned)orec.y;
                    ushort4 sv = *(const ushort4*)&sup[((size_t)(pr & 0xFFFFu) << 7) + r * 4];
                    float v = rec_val(pr);
                    acc.x += v * bf2f(sv.x); acc.y += v * bf2f(sv.y);
                    acc.z += v * bf2f(sv.z); acc.w += v * bf2f(sv.w);
                }
            }
        }

        float4* op = (float4*)&outb[((size_t)row << 7) + r * 4];
        float4 o = *op;
        o.x += acc.x; o.y += acc.y; o.z += acc.z; o.w += acc.w;
        *op = o;
        s4[0] += o.x; s4[1] += o.y; s4[2] += o.z; s4[3] += o.w;
        q4[0] += o.x * o.x; q4[1] += o.y * o.y; q4[2] += o.z * o.z; q4[3] += o.w * o.w;
    }

    #pragma unroll
    for (int j = 0; j < 4; j++) red[slot][r * 4 + j] = s4[j];
    __syncthreads();
    float ts = 0.f;
    if (threadIdx.x < 128) {
        #pragma unroll
        for (int j = 0; j < 8; j++) ts += red[j][threadIdx.x];
    }
    __syncthreads();
    #pragma unroll
    for (int j = 0; j < 4; j++) red[slot][r * 4 + j] = q4[j];
    __syncthreads();
    if (threadIdx.x < 128) {
        float tq = 0.f;
        #pragma unroll
        for (int j = 0; j < 8; j++) tq += red[j][threadIdx.x];
        float* slotp = partials + (size_t)(blockIdx.x & (NSLOT - 1)) * 256;
        atomicAdd(&slotp[threadIdx.x], ts);        // 32 adds/address max
        atomicAdd(&slotp[128 + threadIdx.x], tq);
    }
}

// gemm L1: prologue folds NSLOT partials -> BN scale/shift, then tile
__global__ __launch_bounds__(256) void gemm_bn_k(
    const float* __restrict__ A,
    const unsigned short* __restrict__ Wt, const unsigned short* __restrict__ Wst,
    const float* __restrict__ bias,
    const float* __restrict__ partials, const float* __restrict__ gamma,
    const float* __restrict__ beta, float invN,
    unsigned short* __restrict__ support, float* __restrict__ outb, int N)
{
    __shared__ float tot[256];
    __shared__ float sa[128], sb[128];
    {
        float a = 0.f;
        #pragma unroll 8
        for (int s = 0; s < NSLOT; s++)
            a += partials[(size_t)s * 256 + threadIdx.x];
        tot[threadIdx.x] = a;
    }
    __syncthreads();
    if (threadIdx.x < 128) {
        int c = threadIdx.x;
        float mean = tot[c] * invN;
        float var  = tot[128 + c] * invN - mean * mean;
        float sc   = gamma[c] * rsqrtf(var + BN_EPS);
        sa[c] = sc;
        sb[c] = beta[c] - mean * sc;
    }
    __syncthreads();
    dev_gemm_tile(blockIdx.x, A, Wt, Wst, bias, sa, sb, 1, support, outb, N);
}

// BN(L1) + residual + factorized score; grid-stride, prologue folds partials
__global__ __launch_bounds__(256) void score_k(
    const float* __restrict__ outb, const float* __restrict__ partials,
    const float* __restrict__ gamma, const float* __restrict__ beta,
    const float* __restrict__ x, const float* __restrict__ Wc,
    float* __restrict__ s1, float* __restrict__ s2, float invN, int N)
{
    __shared__ float tot[256];
    __shared__ float sa[128], sb[128];
    {
        float a = 0.f;
        #pragma unroll 8
        for (int s = 0; s < NSLOT; s++)
            a += partials[(size_t)s * 256 + threadIdx.x];
        tot[threadIdx.x] = a;
    }
    __syncthreads();
    if (threadIdx.x < 128) {
        int c = threadIdx.x;
        float mean = tot[c] * invN;
        float var  = tot[128 + c] * invN - mean * mean;
        float sc   = gamma[c] * rsqrtf(var + BN_EPS);
        sa[c] = sc;
        sb[c] = beta[c] - mean * sc;
    }
    __syncthreads();

    int total = N * 32;
    int stride = gridDim.x * 256;
    for (int idx = blockIdx.x * 256 + threadIdx.x; idx < total; idx += stride) {
        int c4 = (idx & 31) * 4;
        float4 o = *(const float4*)&outb[(size_t)idx * 4];
        float res[4];
        const float* op = &o.x;
        #pragma unroll
        for (int j = 0; j < 4; j++) {
            float v = op[j] * sa[c4 + j] + sb[c4 + j];
            res[j] = v > 0.f ? v : 0.f;
        }
        float4 xv = *(const float4*)&x[(size_t)idx * 4];
        res[0] += xv.x; res[1] += xv.y; res[2] += xv.z; res[3] += xv.w;
        float4 w1 = *(const float4*)&Wc[c4];
        float4 w2 = *(const float4*)&Wc[128 + c4];
        float a1 = res[0] * w1.x + res[1] * w1.y + res[2] * w1.z + res[3] * w1.w;
        float a2 = res[0] * w2.x + res[1] * w2.y + res[2] * w2.z + res[3] * w2.w;
        #pragma unroll
        for (int off = 1; off < 32; off <<= 1) {
            a1 += __shfl_xor(a1, off);
            a2 += __shfl_xor(a2, off);
        }
        if ((idx & 31) == 0) {
            int row = idx >> 5;
            s1[row] = a1;
            s2[row] = a2;
        }
    }
}

__global__ __launch_bounds__(256) void edge_pred_k(
    const float* __restrict__ s1, const float* __restrict__ s2,
    const int* __restrict__ ei, const float* __restrict__ bc,
    float* __restrict__ outp, int Ep)
{
    int e = blockIdx.x * 256 + threadIdx.x;
    if (e >= Ep) return;
    float v = s1[ei[e]] + s2[ei[Ep + e]] + bc[0];
    outp[e] = 1.f / (1.f + expf(-v));
}

// ================================================================ launch
extern "C" void kernel_launch(void* const* d_in, const int* in_sizes, int n_in,
                              void* d_out, int out_size, void* d_ws, size_t ws_size,
                              hipStream_t stream) {
    const float* x        = (const float*)d_in[0];
    const int*   adj_row  = (const int*)  d_in[1];
    const int*   adj_col  = (const int*)  d_in[2];
    const float* adj_val  = (const float*)d_in[3];
    const int*   ei       = (const int*)  d_in[4];
    const float* W        = (const float*)d_in[5];
    const float* W_self   = (const float*)d_in[6];
    const float* b        = (const float*)d_in[7];
    const float* gamma    = (const float*)d_in[8];
    const float* beta     = (const float*)d_in[9];
    const float* Wc       = (const float*)d_in[10];
    const float* bc       = (const float*)d_in[11];
    float* outp = (float*)d_out;

    int N  = in_sizes[0] / DD;    // 50000
    int E  = in_sizes[1];         // 800000
    int Ep = in_sizes[4] / 2;     // 500000
    float invN = 1.f / (float)N;

    size_t nd = (size_t)N * DD;
    char* p = (char*)d_ws;
    unsigned short* support16 = (unsigned short*)p; p += nd * 2;
    float*          outbA     = (float*)p;          p += nd * 4;
    float*          outbB     = (float*)p;          p += nd * 4;
    unsigned short* Wt4       = (unsigned short*)p; p += 4 * 16384 * 2;
    // zero region: [partialsA | partialsB | cnt | ovfc] contiguous
    float*          partialsA = (float*)p;          p += (size_t)NSLOT * 256 * 4;
    float*          partialsB = (float*)p;          p += (size_t)NSLOT * 256 * 4;
    int*            cnt       = (int*)p;            p += (size_t)N * 4;
    int*            ovfc      = (int*)p;            p += 4;
    unsigned*       bucket    = (unsigned*)p;       p += (size_t)N * CAP * 4;
    int2*           ovf       = (int2*)p;           p += (size_t)OVF_MAX * 8;
    float*          s1        = (float*)p;          p += (size_t)N * 4;
    float*          s2        = (float*)p;

    int gemm_tiles = (N + 63) / 64;
    int ngroups    = (N + 7) / 8;
    int rpp        = (N + 7) / 8;
    int nz         = NSLOT * 256 * 2 + N + 1;

    prep_zero_k<<<32 + (nz + 255) / 256, 256, 0, stream>>>(
        W, W_self, Wt4, (int*)partialsA, nz);

    // layer 0: scatter + gemm fused, roles interleaved per 8-block group
    gemm_l0_scatter_k<<<FUSE_GRID, 256, 0, stream>>>(
        x, Wt4, Wt4 + 16384, b, support16, outbA, N, gemm_tiles,
        adj_row, adj_col, adj_val, cnt, bucket, ovfc, ovf, E, rpp);
    spmm_stats_k<<<SPMM_BLOCKS, 256, 0, stream>>>(
        cnt, bucket, ovfc, ovf, support16, outbA, partialsA, ngroups, N);

    // layer 1 (BN of L0 folded in prologue)
    gemm_bn_k<<<gemm_tiles, 256, 0, stream>>>(
        outbA, Wt4 + 2 * 16384, Wt4 + 3 * 16384, b + DD,
        partialsA, gamma, beta, invN, support16, outbB, N);
    spmm_stats_k<<<SPMM_BLOCKS, 256, 0, stream>>>(
        cnt, bucket, ovfc, ovf, support16, outbB, partialsB, ngroups, N);

    // final BN + residual + factorized predictor
    score_k<<<2048, 256, 0, stream>>>(
        outbB, partialsB, gamma + DD, beta + DD, x, Wc, s1, s2, invN, N);
    edge_pred_k<<<(Ep + 255) / 256, 256, 0, stream>>>(s1, s2, ei, bc, outp, Ep);
}

// Round 15
// 282.869 us; speedup vs baseline: 7.5619x; 1.3773x over previous
//
#include <hip/hip_runtime.h>
#include <hip/hip_bf16.h>
#include <hip/hip_fp16.h>

#define DD 128
#define BN_EPS 1e-5f
#define SPMM_BLOCKS 2048
#define SCAT_BLOCKS 2048     // 256 slices x 8 partitions
#define NSLOT 64             // stat partial slots
#define CAP 32
#define OVF_MAX 8192

typedef __attribute__((ext_vector_type(8))) short bf16x8;
typedef __attribute__((ext_vector_type(4))) float f32x4;

static __device__ __forceinline__ unsigned short f2bf(float f) {
    __hip_bfloat16 h = __float2bfloat16(f);   // RNE
    return *reinterpret_cast<unsigned short*>(&h);
}
static __device__ __forceinline__ float bf2f(unsigned short u) {
    return __uint_as_float(((unsigned)u) << 16);
}
static __device__ __forceinline__ unsigned pack_rec(int col, float val) {
    __half h = __float2half(val);
    unsigned hb = *reinterpret_cast<unsigned short*>(&h);
    return (unsigned)col | (hb << 16);
}
static __device__ __forceinline__ float rec_val(unsigned rec) {
    unsigned short hb = (unsigned short)(rec >> 16);
    __half h = *reinterpret_cast<__half*>(&hb);
    return __half2float(h);
}

// ---------------------------------------------------------------- prep + zero
__global__ __launch_bounds__(256) void prep_zero_k(
    const float* __restrict__ W, const float* __restrict__ Wself,
    unsigned short* __restrict__ Wt4, int* __restrict__ zp, int nz)
{
    if (blockIdx.x < 32) {
        int mat   = blockIdx.x >> 3;
        int chunk = blockIdx.x & 7;
        int layer = mat >> 1;
        const float* src = (mat & 1) ? (Wself + layer * 16384) : (W + layer * 16384);
        unsigned short* dst = Wt4 + (size_t)mat * 16384;
        int base = chunk * 2048 + threadIdx.x * 4;
        #pragma unroll
        for (int rep = 0; rep < 2; rep++) {
            int i = base + rep * 1024;          // i = k*128 + n
            float4 v = *(const float4*)&src[i];
            int k = i >> 7, n = i & 127;
            dst[(n + 0) * 128 + k] = f2bf(v.x);
            dst[(n + 1) * 128 + k] = f2bf(v.y);
            dst[(n + 2) * 128 + k] = f2bf(v.z);
            dst[(n + 3) * 128 + k] = f2bf(v.w);
        }
    } else {
        int i = (blockIdx.x - 32) * 256 + threadIdx.x;
        if (i < nz) zp[i] = 0;
    }
}

// ---------------------------------------------------------------- scatter body
static __device__ __forceinline__ void scatter_body(
    int j, int nsl, int p,
    const int* __restrict__ arow, const int* __restrict__ acol,
    const float* __restrict__ aval, int* __restrict__ cnt,
    unsigned* __restrict__ bucket, int* __restrict__ ovfc,
    int2* __restrict__ ovf, int E, int rpp)
{
    const int slice = j >> 3;
    const int e0 = (int)((long long)E * slice / nsl);
    const int e1 = (int)((long long)E * (slice + 1) / nsl);
    for (int e = e0 + threadIdx.x; e < e1; e += 256) {
        int r = arow[e];
        if (r / rpp == p) {
            int pos = atomicAdd(&cnt[r], 1);
            unsigned rec = pack_rec(acol[e], aval[e]);
            if (pos < CAP) {
                bucket[(size_t)r * CAP + pos] = rec;
            } else {
                int oi = atomicAdd(ovfc, 1);
                if (oi < OVF_MAX) ovf[oi] = make_int2(r, (int)rec);
            }
        }
    }
}

// ---------------------------------------------------------------- gemm L0 + scatter (R12 verbatim)
// blocks [0, gemm_grid): gemm; blocks [gemm_grid, ..): scatter
__global__ __launch_bounds__(256) void gemm_l0_scatter(
    const float* __restrict__ A,
    const unsigned short* __restrict__ Wt, const unsigned short* __restrict__ Wst,
    const float* __restrict__ bias,
    unsigned short* __restrict__ support, float* __restrict__ outb, int N, int gemm_grid,
    const int* __restrict__ arow, const int* __restrict__ acol,
    const float* __restrict__ aval, int* __restrict__ cnt,
    unsigned* __restrict__ bucket, int* __restrict__ ovfc,
    int2* __restrict__ ovf, int E, int rpp)
{
    if (blockIdx.x >= gemm_grid) {
        int j = blockIdx.x - gemm_grid;
        int nsl = (gridDim.x - gemm_grid) >> 3;
        int p = blockIdx.x & 7;           // XCD-aligned partition
        scatter_body(j, nsl, p, arow, acol, aval, cnt, bucket, ovfc, ovf, E, rpp);
        return;
    }

    const int wave = threadIdx.x >> 6;
    const int lane = threadIdx.x & 63;
    const int m    = lane & 15;
    const int quad = lane >> 4;
    const int row0 = blockIdx.x * 64 + wave * 16;

    int ar = row0 + m; if (ar > N - 1) ar = N - 1;
    const float* Ar = A + (size_t)ar * 128;
    bf16x8 af[4];
    #pragma unroll
    for (int ch = 0; ch < 4; ch++) {
        int k0 = ch * 32 + quad * 8;
        float4 u = *(const float4*)&Ar[k0];
        float4 v = *(const float4*)&Ar[k0 + 4];
        float vals[8] = {u.x, u.y, u.z, u.w, v.x, v.y, v.z, v.w};
        #pragma unroll
        for (int jj = 0; jj < 8; jj++) af[ch][jj] = (short)f2bf(vals[jj]);
    }

    f32x4 acc1[8], acc2[8];
    #pragma unroll
    for (int nt = 0; nt < 8; nt++) { acc1[nt] = (f32x4)(0.f); acc2[nt] = (f32x4)(0.f); }

    #pragma unroll
    for (int nt = 0; nt < 8; nt++) {
        const bf16x8* B1 = (const bf16x8*)(Wt  + ((size_t)(nt * 16 + m)) * 128 + quad * 8);
        const bf16x8* B2 = (const bf16x8*)(Wst + ((size_t)(nt * 16 + m)) * 128 + quad * 8);
        acc1[nt] = __builtin_amdgcn_mfma_f32_16x16x32_bf16(af[0], B1[0],  acc1[nt], 0, 0, 0);
        acc2[nt] = __builtin_amdgcn_mfma_f32_16x16x32_bf16(af[0], B2[0],  acc2[nt], 0, 0, 0);
        acc1[nt] = __builtin_amdgcn_mfma_f32_16x16x32_bf16(af[1], B1[4],  acc1[nt], 0, 0, 0);
        acc2[nt] = __builtin_amdgcn_mfma_f32_16x16x32_bf16(af[1], B2[4],  acc2[nt], 0, 0, 0);
        acc1[nt] = __builtin_amdgcn_mfma_f32_16x16x32_bf16(af[2], B1[8],  acc1[nt], 0, 0, 0);
        acc2[nt] = __builtin_amdgcn_mfma_f32_16x16x32_bf16(af[2], B2[8],  acc2[nt], 0, 0, 0);
        acc1[nt] = __builtin_amdgcn_mfma_f32_16x16x32_bf16(af[3], B1[12], acc1[nt], 0, 0, 0);
        acc2[nt] = __builtin_amdgcn_mfma_f32_16x16x32_bf16(af[3], B2[12], acc2[nt], 0, 0, 0);
    }

    float bv[8];
    #pragma unroll
    for (int nt = 0; nt < 8; nt++) bv[nt] = bias[nt * 16 + m];

    // C/D layout: col = lane&15, row = quad*4 + reg
    #pragma unroll
    for (int r = 0; r < 4; r++) {
        int orow = row0 + quad * 4 + r;
        if (orow < N) {
            size_t base = (size_t)orow * 128 + m;
            #pragma unroll
            for (int nt = 0; nt < 8; nt++) {
                support[base + nt * 16] = f2bf(acc1[nt][r]);
                outb[base + nt * 16]    = acc2[nt][r] + bv[nt];
            }
        }
    }
}

// ---------------------------------------------------------------- gemm L1 + BN prologue (R12 verbatim + fold)
__global__ __launch_bounds__(256) void gemm_bn_k(
    const float* __restrict__ A,
    const unsigned short* __restrict__ Wt, const unsigned short* __restrict__ Wst,
    const float* __restrict__ bias,
    const float* __restrict__ partials, const float* __restrict__ gamma,
    const float* __restrict__ beta, float invN,
    unsigned short* __restrict__ support, float* __restrict__ outb, int N)
{
    __shared__ float tot[256];
    __shared__ float ssc[128], ssh[128];
    {
        float a = 0.f;
        #pragma unroll 8
        for (int s = 0; s < NSLOT; s++)
            a += partials[(size_t)s * 256 + threadIdx.x];
        tot[threadIdx.x] = a;
    }
    __syncthreads();
    if (threadIdx.x < 128) {
        int c = threadIdx.x;
        float mean = tot[c] * invN;
        float var  = tot[128 + c] * invN - mean * mean;
        float sc   = gamma[c] * rsqrtf(var + BN_EPS);
        ssc[c] = sc;
        ssh[c] = beta[c] - mean * sc;
    }
    __syncthreads();

    const int wave = threadIdx.x >> 6;
    const int lane = threadIdx.x & 63;
    const int m    = lane & 15;
    const int quad = lane >> 4;
    const int row0 = blockIdx.x * 64 + wave * 16;

    int ar = row0 + m; if (ar > N - 1) ar = N - 1;
    const float* Ar = A + (size_t)ar * 128;
    bf16x8 af[4];
    #pragma unroll
    for (int ch = 0; ch < 4; ch++) {
        int k0 = ch * 32 + quad * 8;
        float4 u = *(const float4*)&Ar[k0];
        float4 v = *(const float4*)&Ar[k0 + 4];
        float vals[8] = {u.x, u.y, u.z, u.w, v.x, v.y, v.z, v.w};
        #pragma unroll
        for (int j = 0; j < 8; j++) {
            float val = vals[j] * ssc[k0 + j] + ssh[k0 + j];
            val = val > 0.f ? val : 0.f;
            af[ch][j] = (short)f2bf(val);
        }
    }

    f32x4 acc1[8], acc2[8];
    #pragma unroll
    for (int nt = 0; nt < 8; nt++) { acc1[nt] = (f32x4)(0.f); acc2[nt] = (f32x4)(0.f); }

    #pragma unroll
    for (int nt = 0; nt < 8; nt++) {
        const bf16x8* B1 = (const bf16x8*)(Wt  + ((size_t)(nt * 16 + m)) * 128 + quad * 8);
        const bf16x8* B2 = (const bf16x8*)(Wst + ((size_t)(nt * 16 + m)) * 128 + quad * 8);
        acc1[nt] = __builtin_amdgcn_mfma_f32_16x16x32_bf16(af[0], B1[0],  acc1[nt], 0, 0, 0);
        acc2[nt] = __builtin_amdgcn_mfma_f32_16x16x32_bf16(af[0], B2[0],  acc2[nt], 0, 0, 0);
        acc1[nt] = __builtin_amdgcn_mfma_f32_16x16x32_bf16(af[1], B1[4],  acc1[nt], 0, 0, 0);
        acc2[nt] = __builtin_amdgcn_mfma_f32_16x16x32_bf16(af[1], B2[4],  acc2[nt], 0, 0, 0);
        acc1[nt] = __builtin_amdgcn_mfma_f32_16x16x32_bf16(af[2], B1[8],  acc1[nt], 0, 0, 0);
        acc2[nt] = __builtin_amdgcn_mfma_f32_16x16x32_bf16(af[2], B2[8],  acc2[nt], 0, 0, 0);
        acc1[nt] = __builtin_amdgcn_mfma_f32_16x16x32_bf16(af[3], B1[12], acc1[nt], 0, 0, 0);
        acc2[nt] = __builtin_amdgcn_mfma_f32_16x16x32_bf16(af[3], B2[12], acc2[nt], 0, 0, 0);
    }

    float bv[8];
    #pragma unroll
    for (int nt = 0; nt < 8; nt++) bv[nt] = bias[nt * 16 + m];

    #pragma unroll
    for (int r = 0; r < 4; r++) {
        int orow = row0 + quad * 4 + r;
        if (orow < N) {
            size_t base = (size_t)orow * 128 + m;
            #pragma unroll
            for (int nt = 0; nt < 8; nt++) {
                support[base + nt * 16] = f2bf(acc1[nt][r]);
                outb[base + nt * 16]    = acc2[nt][r] + bv[nt];
            }
        }
    }
}

// ---------------------------------------------------------------- SpMM + BN stats (NSLOT partials)
__global__ __launch_bounds__(256) void spmm_stats_k(
    const int* __restrict__ cnt, const unsigned* __restrict__ bucket,
    const int* __restrict__ ovfc, const int2* __restrict__ ovf,
    const unsigned short* __restrict__ sup, float* __restrict__ outb,
    float* __restrict__ partials, int ngroups, int N)
{
    const int r    = threadIdx.x & 31;
    const int slot = threadIdx.x >> 5;
    float s4[4] = {0.f, 0.f, 0.f, 0.f};
    float q4[4] = {0.f, 0.f, 0.f, 0.f};
    __shared__ float red[8][128];

    for (int g = blockIdx.x; g < ngroups; g += gridDim.x) {
        int row = g * 8 + slot;
        if (row >= N) continue;
        int nrec = cnt[row]; if (nrec > CAP) nrec = CAP;
        const unsigned* packed = bucket + (size_t)row * CAP;

        float4 acc = make_float4(0.f, 0.f, 0.f, 0.f);
        int e = 0;
        for (; e + 4 <= nrec; e += 4) {
            unsigned p0 = packed[e + 0];
            unsigned p1 = packed[e + 1];
            unsigned p2 = packed[e + 2];
            unsigned p3 = packed[e + 3];
            ushort4 s0 = *(const ushort4*)&sup[((size_t)(p0 & 0xFFFFu) << 7) + r * 4];
            ushort4 s1 = *(const ushort4*)&sup[((size_t)(p1 & 0xFFFFu) << 7) + r * 4];
            ushort4 s2 = *(const ushort4*)&sup[((size_t)(p2 & 0xFFFFu) << 7) + r * 4];
            ushort4 s3 = *(const ushort4*)&sup[((size_t)(p3 & 0xFFFFu) << 7) + r * 4];
            float v0 = rec_val(p0), v1 = rec_val(p1);
            float v2 = rec_val(p2), v3 = rec_val(p3);
            acc.x += v0 * bf2f(s0.x); acc.y += v0 * bf2f(s0.y);
            acc.z += v0 * bf2f(s0.z); acc.w += v0 * bf2f(s0.w);
            acc.x += v1 * bf2f(s1.x); acc.y += v1 * bf2f(s1.y);
            acc.z += v1 * bf2f(s1.z); acc.w += v1 * bf2f(s1.w);
            acc.x += v2 * bf2f(s2.x); acc.y += v2 * bf2f(s2.y);
            acc.z += v2 * bf2f(s2.z); acc.w += v2 * bf2f(s2.w);
            acc.x += v3 * bf2f(s3.x); acc.y += v3 * bf2f(s3.y);
            acc.z += v3 * bf2f(s3.z); acc.w += v3 * bf2f(s3.w);
        }
        for (; e < nrec; e++) {
            unsigned pr = packed[e];
            ushort4 sv = *(const ushort4*)&sup[((size_t)(pr & 0xFFFFu) << 7) + r * 4];
            float v = rec_val(pr);
            acc.x += v * bf2f(sv.x); acc.y += v * bf2f(sv.y);
            acc.z += v * bf2f(sv.z); acc.w += v * bf2f(sv.w);
        }

        int oc = *ovfc;
        if (oc > 0) {                     // rare exactness safety net
            if (oc > OVF_MAX) oc = OVF_MAX;
            for (int i = 0; i < oc; i++) {
                int2 orec = ovf[i];
                if (orec.x == row) {
                    unsigned pr = (unsigned)orec.y;
                    ushort4 sv = *(const ushort4*)&sup[((size_t)(pr & 0xFFFFu) << 7) + r * 4];
                    float v = rec_val(pr);
                    acc.x += v * bf2f(sv.x); acc.y += v * bf2f(sv.y);
                    acc.z += v * bf2f(sv.z); acc.w += v * bf2f(sv.w);
                }
            }
        }

        float4* op = (float4*)&outb[((size_t)row << 7) + r * 4];
        float4 o = *op;
        o.x += acc.x; o.y += acc.y; o.z += acc.z; o.w += acc.w;
        *op = o;
        s4[0] += o.x; s4[1] += o.y; s4[2] += o.z; s4[3] += o.w;
        q4[0] += o.x * o.x; q4[1] += o.y * o.y; q4[2] += o.z * o.z; q4[3] += o.w * o.w;
    }

    #pragma unroll
    for (int j = 0; j < 4; j++) red[slot][r * 4 + j] = s4[j];
    __syncthreads();
    float ts = 0.f;
    if (threadIdx.x < 128) {
        #pragma unroll
        for (int j = 0; j < 8; j++) ts += red[j][threadIdx.x];
    }
    __syncthreads();
    #pragma unroll
    for (int j = 0; j < 4; j++) red[slot][r * 4 + j] = q4[j];
    __syncthreads();
    if (threadIdx.x < 128) {
        float tq = 0.f;
        #pragma unroll
        for (int j = 0; j < 8; j++) tq += red[j][threadIdx.x];
        float* slotp = partials + (size_t)(blockIdx.x & (NSLOT - 1)) * 256;
        atomicAdd(&slotp[threadIdx.x], ts);        // <=32 adds/address
        atomicAdd(&slotp[128 + threadIdx.x], tq);
    }
}

// ---------------------------------------------------------------- BN(L1)+residual+score
__global__ __launch_bounds__(256) void score_k(
    const float* __restrict__ outb, const float* __restrict__ partials,
    const float* __restrict__ gamma, const float* __restrict__ beta,
    const float* __restrict__ x, const float* __restrict__ Wc,
    float* __restrict__ s1, float* __restrict__ s2, float invN, int N)
{
    __shared__ float tot[256];
    __shared__ float sa[128], sb[128];
    {
        float a = 0.f;
        #pragma unroll 8
        for (int s = 0; s < NSLOT; s++)
            a += partials[(size_t)s * 256 + threadIdx.x];
        tot[threadIdx.x] = a;
    }
    __syncthreads();
    if (threadIdx.x < 128) {
        int c = threadIdx.x;
        float mean = tot[c] * invN;
        float var  = tot[128 + c] * invN - mean * mean;
        float sc   = gamma[c] * rsqrtf(var + BN_EPS);
        sa[c] = sc;
        sb[c] = beta[c] - mean * sc;
    }
    __syncthreads();

    int total = N * 32;
    int stride = gridDim.x * 256;
    for (int idx = blockIdx.x * 256 + threadIdx.x; idx < total; idx += stride) {
        int c4 = (idx & 31) * 4;
        float4 o = *(const float4*)&outb[(size_t)idx * 4];
        float res[4];
        const float* op = &o.x;
        #pragma unroll
        for (int j = 0; j < 4; j++) {
            float v = op[j] * sa[c4 + j] + sb[c4 + j];
            res[j] = v > 0.f ? v : 0.f;
        }
        float4 xv = *(const float4*)&x[(size_t)idx * 4];
        res[0] += xv.x; res[1] += xv.y; res[2] += xv.z; res[3] += xv.w;
        float4 w1 = *(const float4*)&Wc[c4];
        float4 w2 = *(const float4*)&Wc[128 + c4];
        float a1 = res[0] * w1.x + res[1] * w1.y + res[2] * w1.z + res[3] * w1.w;
        float a2 = res[0] * w2.x + res[1] * w2.y + res[2] * w2.z + res[3] * w2.w;
        #pragma unroll
        for (int off = 1; off < 32; off <<= 1) {
            a1 += __shfl_xor(a1, off);
            a2 += __shfl_xor(a2, off);
        }
        if ((idx & 31) == 0) {
            int row = idx >> 5;
            s1[row] = a1;
            s2[row] = a2;
        }
    }
}

__global__ __launch_bounds__(256) void edge_pred_k(
    const float* __restrict__ s1, const float* __restrict__ s2,
    const int* __restrict__ ei, const float* __restrict__ bc,
    float* __restrict__ outp, int Ep)
{
    int e = blockIdx.x * 256 + threadIdx.x;
    if (e >= Ep) return;
    float v = s1[ei[e]] + s2[ei[Ep + e]] + bc[0];
    outp[e] = 1.f / (1.f + expf(-v));
}

// ================================================================ launch
extern "C" void kernel_launch(void* const* d_in, const int* in_sizes, int n_in,
                              void* d_out, int out_size, void* d_ws, size_t ws_size,
                              hipStream_t stream) {
    const float* x        = (const float*)d_in[0];
    const int*   adj_row  = (const int*)  d_in[1];
    const int*   adj_col  = (const int*)  d_in[2];
    const float* adj_val  = (const float*)d_in[3];
    const int*   ei       = (const int*)  d_in[4];
    const float* W        = (const float*)d_in[5];
    const float* W_self   = (const float*)d_in[6];
    const float* b        = (const float*)d_in[7];
    const float* gamma    = (const float*)d_in[8];
    const float* beta     = (const float*)d_in[9];
    const float* Wc       = (const float*)d_in[10];
    const float* bc       = (const float*)d_in[11];
    float* outp = (float*)d_out;

    int N  = in_sizes[0] / DD;    // 50000
    int E  = in_sizes[1];         // 800000
    int Ep = in_sizes[4] / 2;     // 500000
    float invN = 1.f / (float)N;

    size_t nd = (size_t)N * DD;
    char* p = (char*)d_ws;
    unsigned short* support16 = (unsigned short*)p; p += nd * 2;
    float*          outbA     = (float*)p;          p += nd * 4;
    float*          outbB     = (float*)p;          p += nd * 4;
    unsigned short* Wt4       = (unsigned short*)p; p += 4 * 16384 * 2;
    // zero region: [partialsA | partialsB | cnt | ovfc] contiguous
    float*          partialsA = (float*)p;          p += (size_t)NSLOT * 256 * 4;
    float*          partialsB = (float*)p;          p += (size_t)NSLOT * 256 * 4;
    int*            cnt       = (int*)p;            p += (size_t)N * 4;
    int*            ovfc      = (int*)p;            p += 4;
    unsigned*       bucket    = (unsigned*)p;       p += (size_t)N * CAP * 4;
    int2*           ovf       = (int2*)p;           p += (size_t)OVF_MAX * 8;
    float*          s1        = (float*)p;          p += (size_t)N * 4;
    float*          s2        = (float*)p;

    int gemm_tiles = (N + 63) / 64;
    int ngroups    = (N + 7) / 8;
    int rpp        = (N + 7) / 8;
    int nz         = NSLOT * 256 * 2 + N + 1;

    prep_zero_k<<<32 + (nz + 255) / 256, 256, 0, stream>>>(
        W, W_self, Wt4, (int*)partialsA, nz);

    // layer 0: gemm blocks first, scatter blocks after (R12 structure, VGPR 48)
    gemm_l0_scatter<<<gemm_tiles + SCAT_BLOCKS, 256, 0, stream>>>(
        x, Wt4, Wt4 + 16384, b, support16, outbA, N, gemm_tiles,
        adj_row, adj_col, adj_val, cnt, bucket, ovfc, ovf, E, rpp);
    spmm_stats_k<<<SPMM_BLOCKS, 256, 0, stream>>>(
        cnt, bucket, ovfc, ovf, support16, outbA, partialsA, ngroups, N);

    // layer 1 (BN of L0 folded in prologue)
    gemm_bn_k<<<gemm_tiles, 256, 0, stream>>>(
        outbA, Wt4 + 2 * 16384, Wt4 + 3 * 16384, b + DD,
        partialsA, gamma, beta, invN, support16, outbB, N);
    spmm_stats_k<<<SPMM_BLOCKS, 256, 0, stream>>>(
        cnt, bucket, ovfc, ovf, support16, outbB, partialsB, ngroups, N);

    // final BN + residual + factorized predictor
    score_k<<<2048, 256, 0, stream>>>(
        outbB, partialsB, gamma + DD, beta + DD, x, Wc, s1, s2, invN, N);
    edge_pred_k<<<(Ep + 255) / 256, 256, 0, stream>>>(s1, s2, ei, bc, outp, Ep);
}